// Round 1
// baseline (204.966 us; speedup 1.0000x reference)
//
#include <hip/hip_runtime.h>

// SAUCD simp_wt scoring: score[b,m] = clip( sum_l |w|[bin(lmbd[b,m,l+1])] * N[b,m,l] * areas[b,m,l], 0, 2 )
// B=8, M=16, L=131072 -> 128 rows of 131072.

#define N_ROWS 128
#define ROW_L 131072
#define BLOCKS_PER_ROW 16
#define TPB 256
#define ELEMS_PER_THREAD 32   // (ROW_L / BLOCKS_PER_ROW) / TPB = 8192/256

__global__ __launch_bounds__(TPB) void saucd_reduce_kernel(
    const float* __restrict__ weight,      // [64]
    const float* __restrict__ narr,        // [128, 131072]
    const float* __restrict__ lmbd,        // [128, 131073]
    const float* __restrict__ areas,       // [128, 131072]
    float* __restrict__ out)               // [128], pre-zeroed
{
    __shared__ float w_abs[64];
    if (threadIdx.x < 64) w_abs[threadIdx.x] = fabsf(weight[threadIdx.x]);
    __syncthreads();

    const int row = blockIdx.y;
    const long long row_base  = (long long)row * ROW_L;
    const long long lmbd_base = (long long)row * (ROW_L + 1) + 1;  // skip sorted_lmbd[...,0]
    const int chunk = blockIdx.x * (TPB * ELEMS_PER_THREAD) + threadIdx.x;

    float acc = 0.0f;
#pragma unroll
    for (int k = 0; k < ELEMS_PER_THREAD; ++k) {
        const int e = chunk + k * TPB;                 // coalesced: lane i -> consecutive floats
        const float l = lmbd[lmbd_base + e];
        const float n = narr[row_base + e];
        const float a = areas[row_base + e];
        // bin: clamp(floor((log(clip(l,1e-8)) - (-6.0)) / 0.105), 0, 63)
        const float logl = logf(fmaxf(l, 1e-8f));
        const float t = (logl + 6.0f) / 0.105f;        // IEEE divide, matches reference binning
        int idx = (int)floorf(t);
        idx = min(max(idx, 0), 63);
        acc = fmaf(w_abs[idx] * n, a, acc);
    }

    // wave (64-lane) butterfly reduce
#pragma unroll
    for (int off = 32; off > 0; off >>= 1)
        acc += __shfl_down(acc, off, 64);

    __shared__ float wave_sum[TPB / 64];
    const int lane = threadIdx.x & 63;
    const int wid  = threadIdx.x >> 6;
    if (lane == 0) wave_sum[wid] = acc;
    __syncthreads();
    if (threadIdx.x == 0) {
        float s = wave_sum[0] + wave_sum[1] + wave_sum[2] + wave_sum[3];
        atomicAdd(&out[row], s);   // 16 atomics/row total — negligible contention
    }
}

__global__ void saucd_finalize_kernel(float* __restrict__ out, int n) {
    const int i = threadIdx.x + blockIdx.x * blockDim.x;
    if (i < n) out[i] = fminf(fmaxf(out[i], 0.0f), 2.0f);
}

extern "C" void kernel_launch(void* const* d_in, const int* in_sizes, int n_in,
                              void* d_out, int out_size, void* d_ws, size_t ws_size,
                              hipStream_t stream) {
    const float* weight = (const float*)d_in[0];   // [64]
    const float* narr   = (const float*)d_in[1];   // [8,16,131072]
    const float* lmbd   = (const float*)d_in[2];   // [8,16,131073]
    const float* areas  = (const float*)d_in[3];   // [8,16,131072]
    float* out = (float*)d_out;                    // [128] f32

    // d_out is poisoned 0xAA before every call — zero it for the atomic accumulate.
    hipMemsetAsync(out, 0, (size_t)out_size * sizeof(float), stream);

    dim3 grid(BLOCKS_PER_ROW, N_ROWS);
    saucd_reduce_kernel<<<grid, TPB, 0, stream>>>(weight, narr, lmbd, areas, out);
    saucd_finalize_kernel<<<1, 128, 0, stream>>>(out, out_size);
}

// Round 2
// 200.508 us; speedup vs baseline: 1.0222x; 1.0222x over previous
//
#include <hip/hip_runtime.h>

// SAUCD simp_wt scoring: score[b,m] = clip( sum_l |w|[bin(lmbd[b,m,l+1])] * N[b,m,l] * areas[b,m,l], 0, 2 )
// B=8, M=16, L=131072 -> 128 rows of 131072 elements.
//
// R1: latency-bound fix — float4 vector loads + explicit double-buffer prefetch
// (3 wide loads in flight per wave), cheap binning (mul-by-recip, __logf,
// clamp-then-trunc). Elementwise streams are read once; target ~32 us roofline.

#define N_ROWS 128
#define ROW_L 131072
#define BLOCKS_PER_ROW 16
#define TPB 256
#define CHUNK (ROW_L / BLOCKS_PER_ROW)      // 8192 elements per block
#define GROUPS (CHUNK / (TPB * 4))          // 8 float4-groups per thread

__device__ __forceinline__ int wbin(float l) {
    // clamp(floor((log(max(l,1e-8)) + 6.0) / 0.105), 0, 63)
    const float logl = __logf(fmaxf(l, 1e-8f));
    const float t = (logl + 6.0f) * 9.52380952380952381f;   // 1/0.105
    // clamp-then-trunc == floor-then-clamp for t<0 (->0), 0<=t<64, t>=64 (->63)
    return (int)fminf(fmaxf(t, 0.0f), 63.0f);
}

__global__ __launch_bounds__(TPB) void saucd_reduce_kernel(
    const float* __restrict__ weight,      // [64]
    const float* __restrict__ narr,        // [128, 131072]
    const float* __restrict__ lmbd,        // [128, 131073]
    const float* __restrict__ areas,       // [128, 131072]
    float* __restrict__ out)               // [128], pre-zeroed
{
    __shared__ float w_abs[64];
    if (threadIdx.x < 64) w_abs[threadIdx.x] = fabsf(weight[threadIdx.x]);
    __syncthreads();

    const int row = blockIdx.y;
    const size_t blk = (size_t)row * ROW_L + (size_t)blockIdx.x * CHUNK;
    const float4* __restrict__ narr4  = (const float4*)(narr  + blk);   // 16B-aligned
    const float4* __restrict__ areas4 = (const float4*)(areas + blk);   // 16B-aligned
    const float*  __restrict__ lp     = lmbd + (size_t)row * (ROW_L + 1) + 1
                                             + (size_t)blockIdx.x * CHUNK;  // odd offset

    float acc0 = 0.0f, acc1 = 0.0f, acc2 = 0.0f, acc3 = 0.0f;

    // double-buffered prefetch: keep next group's 3 wide loads in flight
    int g = threadIdx.x;
    float4 nv = narr4[g];
    float4 av = areas4[g];
    float4 lv;
    __builtin_memcpy(&lv, lp + 4 * g, 16);

#pragma unroll
    for (int k = 0; k < GROUPS; ++k) {
        const float4 cn = nv, ca = av, cl = lv;
        if (k + 1 < GROUPS) {
            const int g2 = g + TPB;
            nv = narr4[g2];
            av = areas4[g2];
            __builtin_memcpy(&lv, lp + 4 * g2, 16);
            g = g2;
        }
        acc0 = fmaf(w_abs[wbin(cl.x)] * cn.x, ca.x, acc0);
        acc1 = fmaf(w_abs[wbin(cl.y)] * cn.y, ca.y, acc1);
        acc2 = fmaf(w_abs[wbin(cl.z)] * cn.z, ca.z, acc2);
        acc3 = fmaf(w_abs[wbin(cl.w)] * cn.w, ca.w, acc3);
    }

    float acc = (acc0 + acc1) + (acc2 + acc3);

    // wave (64-lane) butterfly reduce
#pragma unroll
    for (int off = 32; off > 0; off >>= 1)
        acc += __shfl_down(acc, off, 64);

    __shared__ float wave_sum[TPB / 64];
    const int lane = threadIdx.x & 63;
    const int wid  = threadIdx.x >> 6;
    if (lane == 0) wave_sum[wid] = acc;
    __syncthreads();
    if (threadIdx.x == 0) {
        float s = (wave_sum[0] + wave_sum[1]) + (wave_sum[2] + wave_sum[3]);
        atomicAdd(&out[row], s);   // 16 atomics/row — negligible contention
    }
}

__global__ void saucd_finalize_kernel(float* __restrict__ out, int n) {
    const int i = threadIdx.x + blockIdx.x * blockDim.x;
    if (i < n) out[i] = fminf(fmaxf(out[i], 0.0f), 2.0f);
}

extern "C" void kernel_launch(void* const* d_in, const int* in_sizes, int n_in,
                              void* d_out, int out_size, void* d_ws, size_t ws_size,
                              hipStream_t stream) {
    const float* weight = (const float*)d_in[0];   // [64]
    const float* narr   = (const float*)d_in[1];   // [8,16,131072]
    const float* lmbd   = (const float*)d_in[2];   // [8,16,131073]
    const float* areas  = (const float*)d_in[3];   // [8,16,131072]
    float* out = (float*)d_out;                    // [128] f32

    // d_out is poisoned 0xAA before every call — zero it for the atomic accumulate.
    hipMemsetAsync(out, 0, (size_t)out_size * sizeof(float), stream);

    dim3 grid(BLOCKS_PER_ROW, N_ROWS);
    saucd_reduce_kernel<<<grid, TPB, 0, stream>>>(weight, narr, lmbd, areas, out);
    saucd_finalize_kernel<<<1, 128, 0, stream>>>(out, out_size);
}